// Round 15
// baseline (378.916 us; speedup 1.0000x reference)
//
#include <hip/hip_runtime.h>
#include <math.h>

#define N_NODES 100000
#define N_EDGES 3200000
#define F_IN    512
#define H1      16
#define H2      40

#define NB      391      // coarse buckets: dst >> 8, 256 nodes each
#define BSH     8
#define BMASK   255
#define B1      512      // scatter blocks
#define EPB     6250     // edges per block (512*6250 = 3.2M exactly)
#define CAP     9216     // bucket slot capacity: mean 8192 + 11 sigma (fixed input)

// ---------------------------------------------------------------------------
// Detect edge_index dtype (int64 vs int32) and zero the bucket counters.
__global__ void detect_idx_kernel(const int* __restrict__ ei, int* __restrict__ flag,
                                  int* __restrict__ cnt)
{
    for (int i = threadIdx.x; i < 512; i += 64) cnt[i] = 0;
    if (threadIdx.x == 0) {
        int all_zero = 1;
        for (int i = 0; i < 64; ++i)
            if (ei[2 * i + 1] != 0) { all_zero = 0; break; }
        *flag = all_zero;  // 1 => int64 layout, 0 => int32 layout
    }
}

__device__ __forceinline__ int edge_src(const void* ei, int e, int is64)
{
    return is64 ? (int)((const long long*)ei)[e] : ((const int*)ei)[e];
}
__device__ __forceinline__ int edge_dst(const void* ei, int e, int is64)
{
    return is64 ? (int)((const long long*)ei)[N_EDGES + e]
                : ((const int*)ei)[N_EDGES + e];
}

// ---------------------------------------------------------------------------
// Bucket scatter: LDS histogram; one global atomicAdd per touched bucket
// reserves this block's range in the bucket's CAP slot; LDS-cursor scatter.
__global__ __launch_bounds__(256) void scatter_atomic_kernel(
    const void* __restrict__ ei, const int* __restrict__ flag,
    int* __restrict__ cnt, int* __restrict__ packed)
{
    __shared__ int h[NB];
    __shared__ int cur[NB];
    for (int i = threadIdx.x; i < NB; i += 256) h[i] = 0;
    __syncthreads();
    const int is64 = *flag;
    const int e0 = blockIdx.x * EPB;
    for (int i = threadIdx.x; i < EPB; i += 256) {
        int e = e0 + i;
        if (e < N_EDGES) atomicAdd(&h[edge_dst(ei, e, is64) >> BSH], 1);
    }
    __syncthreads();
    for (int i = threadIdx.x; i < NB; i += 256) {
        int base = (h[i] > 0) ? atomicAdd(&cnt[i], h[i]) : 0;
        cur[i] = i * CAP + base;
    }
    __syncthreads();
    for (int i = threadIdx.x; i < EPB; i += 256) {
        int e = e0 + i;
        if (e >= N_EDGES) break;
        const int s = edge_src(ei, e, is64);
        const int d = edge_dst(ei, e, is64);
        const int pos = atomicAdd(&cur[d >> BSH], 1);
        packed[pos] = (s << BSH) | (d & BMASK);
    }
}

// ---------------------------------------------------------------------------
// One block per bucket: dense-csr base = wave-sum cnt[0..b); LDS hist+scan+
// scatter. Emits deg[], row_beg[] (global), csr[].
__global__ __launch_bounds__(512) void bucket_csr_kernel(
    const int* __restrict__ packed, const int* __restrict__ cnt,
    int* __restrict__ deg, int* __restrict__ row_beg, int* __restrict__ csr)
{
    __shared__ int hist[256];
    __shared__ int off[256];
    __shared__ int sbase;
    const int b   = blockIdx.x;
    const int tid = threadIdx.x;

    if (tid < 64) {
        int s = 0;
        for (int i = tid; i < b; i += 64) s += cnt[i];
        #pragma unroll
        for (int o = 32; o > 0; o >>= 1) s += __shfl_xor(s, o, 64);
        if (tid == 0) sbase = s;
    }
    if (tid < 256) hist[tid] = 0;
    __syncthreads();

    const int base_in = b * CAP;
    const int m       = cnt[b];
    for (int i = tid; i < m; i += 512)
        atomicAdd(&hist[packed[base_in + i] & BMASK], 1);
    __syncthreads();

    int v = 0;
    if (tid < 256) { v = hist[tid]; off[tid] = v; }
    __syncthreads();
    for (int o = 1; o < 256; o <<= 1) {
        int t2 = 0;
        if (tid < 256 && tid >= o) t2 = off[tid - o];
        __syncthreads();
        if (tid < 256) off[tid] += t2;
        __syncthreads();
    }
    if (tid < 256) {
        const int excl = sbase + off[tid] - v;
        const int g = (b << BSH) + tid;
        if (g < N_NODES) { deg[g] = v; row_beg[g] = excl; }
        off[tid] = excl;
    }
    __syncthreads();
    for (int i = tid; i < m; i += 512) {
        const int p = packed[base_in + i];
        const int pos = atomicAdd(&off[p & BMASK], 1);
        csr[pos] = p >> BSH;
    }
}

// ---------------------------------------------------------------------------
// hs1[r][j] = (x[r] @ W1)[j] * dis[r];  dis[r] = rsqrt(deg[r]+1)
// Wave-paired split-K: waves {0,1} cover rows [0,64) with K-halves {0,1},
// waves {2,3} rows [64,128). half = wave&1 keeps W addresses wave-uniform
// (scalarized s_load path preserved). 2x waves/CU vs thread-per-row
// (12.2 vs 6.1) -> 2x in-flight x-lines; per-thread loop body identical
// to the proven r12 pattern. Combine via padded LDS (stride 17, no bank
// conflicts) + one barrier; no global partials, no extra fetch.
__global__ __launch_bounds__(256) void gemm1_kernel(
    const float* __restrict__ x, const float* __restrict__ W1,
    const int* __restrict__ deg, float* __restrict__ hs1,
    float* __restrict__ dis, int n)
{
    __shared__ float accL[2][64][17];              // 8.7 KB
    const int tid  = threadIdx.x;
    const int wave = tid >> 6;
    const int lane = tid & 63;
    const int rgrp = wave >> 1;
    const int half = wave & 1;
    const int r    = blockIdx.x * 128 + rgrp * 64 + lane;

    float acc[H1];
    #pragma unroll
    for (int j = 0; j < H1; ++j) acc[j] = 0.f;

    if (r < n) {
        const float4* xr = (const float4*)(x + (size_t)r * F_IN) + half * 64;
        const float*  Wb = W1 + half * 64 * 4 * H1;
        #pragma unroll 2
        for (int k4 = 0; k4 < 64; ++k4) {
            const float4 xv = xr[k4];
            const float* wk = Wb + k4 * 4 * H1;    // wave-uniform address
            #pragma unroll
            for (int j = 0; j < H1; ++j)
                acc[j] += xv.x * wk[j] + xv.y * wk[H1 + j]
                        + xv.z * wk[2 * H1 + j] + xv.w * wk[3 * H1 + j];
        }
    }

    if (half == 1) {
        #pragma unroll
        for (int j = 0; j < H1; ++j) accL[rgrp][lane][j] = acc[j];
    }
    __syncthreads();
    if (half == 0 && r < n) {
        const float dv = rsqrtf((float)deg[r] + 1.0f);
        dis[r] = dv;
        float4* o = (float4*)(hs1 + (size_t)r * H1);
        #pragma unroll
        for (int q = 0; q < 4; ++q) {
            float4 v;
            v.x = (acc[4 * q + 0] + accL[rgrp][lane][4 * q + 0]) * dv;
            v.y = (acc[4 * q + 1] + accL[rgrp][lane][4 * q + 1]) * dv;
            v.z = (acc[4 * q + 2] + accL[rgrp][lane][4 * q + 2]) * dv;
            v.w = (acc[4 * q + 3] + accL[rgrp][lane][4 * q + 3]) * dv;
            o[q] = v;
        }
    }
}

// ---------------------------------------------------------------------------
// Pull1: 4-lane group per node; unroll-4 with batched index loads.
// Epilogue: c = dis * relu(dis*(acc + hs1_self) + b1).
__global__ __launch_bounds__(256) void pull1_kernel(
    const int* __restrict__ row_beg, const int* __restrict__ deg,
    const int* __restrict__ csr, const float* __restrict__ rows,
    const float* __restrict__ dis, const float* __restrict__ b1,
    float* __restrict__ out, int n)
{
    int t = blockIdx.x * 256 + threadIdx.x;
    int g = t >> 2;
    int q = t & 3;
    if (g >= n) return;
    const int beg = row_beg[g];
    const int end = beg + deg[g];
    float4 a0 = make_float4(0.f, 0.f, 0.f, 0.f);
    float4 a1 = make_float4(0.f, 0.f, 0.f, 0.f);
    int i = beg;
    for (; i + 3 < end; i += 4) {
        const int s0 = csr[i], s1 = csr[i + 1], s2 = csr[i + 2], s3 = csr[i + 3];
        float4 v0 = ((const float4*)(rows + (size_t)s0 * H1))[q];
        float4 v1 = ((const float4*)(rows + (size_t)s1 * H1))[q];
        float4 v2 = ((const float4*)(rows + (size_t)s2 * H1))[q];
        float4 v3 = ((const float4*)(rows + (size_t)s3 * H1))[q];
        a0.x += v0.x + v2.x; a0.y += v0.y + v2.y; a0.z += v0.z + v2.z; a0.w += v0.w + v2.w;
        a1.x += v1.x + v3.x; a1.y += v1.y + v3.y; a1.z += v1.z + v3.z; a1.w += v1.w + v3.w;
    }
    for (; i < end; ++i) {
        float4 v = ((const float4*)(rows + (size_t)csr[i] * H1))[q];
        a0.x += v.x; a0.y += v.y; a0.z += v.z; a0.w += v.w;
    }
    a0.x += a1.x; a0.y += a1.y; a0.z += a1.z; a0.w += a1.w;

    const float dv = dis[g];
    float4 h = ((const float4*)(rows + (size_t)g * H1))[q];  // self-loop
    float4 bq = ((const float4*)b1)[q];
    a0.x = dv * fmaxf(dv * (a0.x + h.x) + bq.x, 0.f);
    a0.y = dv * fmaxf(dv * (a0.y + h.y) + bq.y, 0.f);
    a0.z = dv * fmaxf(dv * (a0.z + h.z) + bq.z, 0.f);
    a0.w = dv * fmaxf(dv * (a0.w + h.w) + bq.w, 0.f);
    ((float4*)(out + (size_t)g * H1))[q] = a0;
}

// ---------------------------------------------------------------------------
// Fused pull2 + layer-2 epilogue: aggregate c (16-dim) per node, swap the
// full t[16] across the 4-lane group (12 shfl), apply W2 + b2 + log_softmax
// in-group, write out directly.
__global__ __launch_bounds__(256) void pull2_epi_kernel(
    const int* __restrict__ row_beg, const int* __restrict__ deg,
    const int* __restrict__ csr, const float* __restrict__ c,
    const float* __restrict__ W2, const float* __restrict__ b2,
    const float* __restrict__ dis, float* __restrict__ out, int n)
{
    __shared__ float w[H1 * H2];   // [16][40]
    __shared__ float bb[H2];
    for (int i = threadIdx.x; i < H1 * H2; i += 256) w[i] = W2[i];
    if (threadIdx.x < H2) bb[threadIdx.x] = b2[threadIdx.x];
    __syncthreads();

    int t = blockIdx.x * 256 + threadIdx.x;
    int g = t >> 2;
    int q = t & 3;
    if (g >= n) return;
    const int beg = row_beg[g];
    const int end = beg + deg[g];
    float4 a0 = make_float4(0.f, 0.f, 0.f, 0.f);
    float4 a1 = make_float4(0.f, 0.f, 0.f, 0.f);
    int i = beg;
    for (; i + 3 < end; i += 4) {
        const int s0 = csr[i], s1 = csr[i + 1], s2 = csr[i + 2], s3 = csr[i + 3];
        float4 v0 = ((const float4*)(c + (size_t)s0 * H1))[q];
        float4 v1 = ((const float4*)(c + (size_t)s1 * H1))[q];
        float4 v2 = ((const float4*)(c + (size_t)s2 * H1))[q];
        float4 v3 = ((const float4*)(c + (size_t)s3 * H1))[q];
        a0.x += v0.x + v2.x; a0.y += v0.y + v2.y; a0.z += v0.z + v2.z; a0.w += v0.w + v2.w;
        a1.x += v1.x + v3.x; a1.y += v1.y + v3.y; a1.z += v1.z + v3.z; a1.w += v1.w + v3.w;
    }
    for (; i < end; ++i) {
        float4 v = ((const float4*)(c + (size_t)csr[i] * H1))[q];
        a0.x += v.x; a0.y += v.y; a0.z += v.z; a0.w += v.w;
    }
    float4 sv = ((const float4*)(c + (size_t)g * H1))[q];    // self term
    float4 acc;
    acc.x = a0.x + a1.x + sv.x;
    acc.y = a0.y + a1.y + sv.y;
    acc.z = a0.z + a1.z + sv.z;
    acc.w = a0.w + a1.w + sv.w;

    // gather full t[16] across the aligned 4-lane group
    float tt[16];
    tt[4 * q + 0] = acc.x; tt[4 * q + 1] = acc.y;
    tt[4 * q + 2] = acc.z; tt[4 * q + 3] = acc.w;
    #pragma unroll
    for (int p = 1; p < 4; ++p) {
        const int qq = q ^ p;
        tt[4 * qq + 0] = __shfl_xor(acc.x, p, 64);
        tt[4 * qq + 1] = __shfl_xor(acc.y, p, 64);
        tt[4 * qq + 2] = __shfl_xor(acc.z, p, 64);
        tt[4 * qq + 3] = __shfl_xor(acc.w, p, 64);
    }

    const float dv = dis[g];
    float val[10];
    float m = -INFINITY;
    #pragma unroll
    for (int u = 0; u < 10; ++u) {
        const int j = q * 10 + u;
        float s = 0.f;
        #pragma unroll
        for (int k = 0; k < H1; ++k) s += tt[k] * w[k * H2 + j];
        val[u] = dv * s + bb[j];
        m = fmaxf(m, val[u]);
    }
    m = fmaxf(m, __shfl_xor(m, 1, 64));
    m = fmaxf(m, __shfl_xor(m, 2, 64));
    float ex = 0.f;
    #pragma unroll
    for (int u = 0; u < 10; ++u) ex += __expf(val[u] - m);
    ex += __shfl_xor(ex, 1, 64);
    ex += __shfl_xor(ex, 2, 64);
    const float lse = m + logf(ex);

    float2* o = (float2*)(out + (size_t)g * H2 + q * 10);
    #pragma unroll
    for (int u = 0; u < 5; ++u) {
        float2 v;
        v.x = val[2 * u]     - lse;
        v.y = val[2 * u + 1] - lse;
        o[u] = v;
    }
}

// ---------------------------------------------------------------------------
extern "C" void kernel_launch(void* const* d_in, const int* in_sizes, int n_in,
                              void* d_out, int out_size, void* d_ws, size_t ws_size,
                              hipStream_t stream)
{
    const float* x   = (const float*)d_in[0];
    const void*  ei  = d_in[1];                 // int32 or int64 [2, E] — detected
    const float* W1  = (const float*)d_in[2];
    const float* b1  = (const float*)d_in[3];
    const float* W2  = (const float*)d_in[4];
    const float* b2  = (const float*)d_in[5];
    float*       out = (float*)d_out;

    // workspace layout (4-byte units); ~28.4 MB, float4-aligned slabs.
    // packed (391*CAP slotted, 14.4MB) is time-multiplexed:
    //   CSR build: packed;   gemm1/pulls: hs1/c overlay its first 12.8MB
    int*   base    = (int*)d_ws;
    int*   flag    = base;                                  // 16
    int*   deg     = base + 16;                             // N
    int*   row_beg = deg + N_NODES;                         // N
    int*   cnt     = row_beg + N_NODES;                     // 512 (NB used)
    float* dis     = (float*)(cnt + 512);                   // N
    int*   csr     = (int*)(dis + N_NODES);                 // E (dense)
    int*   packed  = csr + N_EDGES;                         // NB*CAP (slotted)
    float* hs1     = (float*)packed;                        // N*16 overlay
    float* c       = hs1 + (size_t)N_NODES * H1;            // N*16 overlay

    detect_idx_kernel<<<1, 64, 0, stream>>>((const int*)ei, flag, cnt);

    scatter_atomic_kernel<<<B1, 256, 0, stream>>>(ei, flag, cnt, packed);
    bucket_csr_kernel<<<NB, 512, 0, stream>>>(packed, cnt, deg, row_beg, csr);

    gemm1_kernel<<<(N_NODES + 127) / 128, 256, 0, stream>>>(x, W1, deg, hs1, dis, N_NODES);

    const int PB = (N_NODES * 4 + 255) / 256;
    pull1_kernel<<<PB, 256, 0, stream>>>(row_beg, deg, csr, hs1, dis, b1, c, N_NODES);
    pull2_epi_kernel<<<PB, 256, 0, stream>>>(row_beg, deg, csr, c, W2, b2, dis, out, N_NODES);
}

// Round 16
// 304.583 us; speedup vs baseline: 1.2441x; 1.2441x over previous
//
#include <hip/hip_runtime.h>
#include <math.h>

#define N_NODES 100000
#define N_EDGES 3200000
#define F_IN    512
#define H1      16
#define H2      40

#define NB      391      // coarse buckets: dst >> 8, 256 nodes each
#define BSH     8
#define BMASK   255
#define B1      512      // scatter blocks
#define EPB     6250     // edges per block (512*6250 = 3.2M exactly)
#define CAP     9216     // bucket slot capacity: mean 8192 + 11 sigma (fixed input)

#define GR      128      // gemm1 rows per block
#define GKT     32       // gemm1 k-floats per tile
#define GNT     (F_IN / GKT)   // 16 tiles

// ---------------------------------------------------------------------------
// Detect edge_index dtype (int64 vs int32) and zero the bucket counters.
__global__ void detect_idx_kernel(const int* __restrict__ ei, int* __restrict__ flag,
                                  int* __restrict__ cnt)
{
    for (int i = threadIdx.x; i < 512; i += 64) cnt[i] = 0;
    if (threadIdx.x == 0) {
        int all_zero = 1;
        for (int i = 0; i < 64; ++i)
            if (ei[2 * i + 1] != 0) { all_zero = 0; break; }
        *flag = all_zero;  // 1 => int64 layout, 0 => int32 layout
    }
}

__device__ __forceinline__ int edge_src(const void* ei, int e, int is64)
{
    return is64 ? (int)((const long long*)ei)[e] : ((const int*)ei)[e];
}
__device__ __forceinline__ int edge_dst(const void* ei, int e, int is64)
{
    return is64 ? (int)((const long long*)ei)[N_EDGES + e]
                : ((const int*)ei)[N_EDGES + e];
}

// ---------------------------------------------------------------------------
// Bucket scatter: LDS histogram; one global atomicAdd per touched bucket
// reserves this block's range in the bucket's CAP slot; LDS-cursor scatter.
__global__ __launch_bounds__(256) void scatter_atomic_kernel(
    const void* __restrict__ ei, const int* __restrict__ flag,
    int* __restrict__ cnt, int* __restrict__ packed)
{
    __shared__ int h[NB];
    __shared__ int cur[NB];
    for (int i = threadIdx.x; i < NB; i += 256) h[i] = 0;
    __syncthreads();
    const int is64 = *flag;
    const int e0 = blockIdx.x * EPB;
    for (int i = threadIdx.x; i < EPB; i += 256) {
        int e = e0 + i;
        if (e < N_EDGES) atomicAdd(&h[edge_dst(ei, e, is64) >> BSH], 1);
    }
    __syncthreads();
    for (int i = threadIdx.x; i < NB; i += 256) {
        int base = (h[i] > 0) ? atomicAdd(&cnt[i], h[i]) : 0;
        cur[i] = i * CAP + base;
    }
    __syncthreads();
    for (int i = threadIdx.x; i < EPB; i += 256) {
        int e = e0 + i;
        if (e >= N_EDGES) break;
        const int s = edge_src(ei, e, is64);
        const int d = edge_dst(ei, e, is64);
        const int pos = atomicAdd(&cur[d >> BSH], 1);
        packed[pos] = (s << BSH) | (d & BMASK);
    }
}

// ---------------------------------------------------------------------------
// One block per bucket: dense-csr base = wave-sum cnt[0..b); LDS hist+scan+
// scatter. Emits deg[], row_beg[] (global), csr[].
__global__ __launch_bounds__(512) void bucket_csr_kernel(
    const int* __restrict__ packed, const int* __restrict__ cnt,
    int* __restrict__ deg, int* __restrict__ row_beg, int* __restrict__ csr)
{
    __shared__ int hist[256];
    __shared__ int off[256];
    __shared__ int sbase;
    const int b   = blockIdx.x;
    const int tid = threadIdx.x;

    if (tid < 64) {
        int s = 0;
        for (int i = tid; i < b; i += 64) s += cnt[i];
        #pragma unroll
        for (int o = 32; o > 0; o >>= 1) s += __shfl_xor(s, o, 64);
        if (tid == 0) sbase = s;
    }
    if (tid < 256) hist[tid] = 0;
    __syncthreads();

    const int base_in = b * CAP;
    const int m       = cnt[b];
    for (int i = tid; i < m; i += 512)
        atomicAdd(&hist[packed[base_in + i] & BMASK], 1);
    __syncthreads();

    int v = 0;
    if (tid < 256) { v = hist[tid]; off[tid] = v; }
    __syncthreads();
    for (int o = 1; o < 256; o <<= 1) {
        int t2 = 0;
        if (tid < 256 && tid >= o) t2 = off[tid - o];
        __syncthreads();
        if (tid < 256) off[tid] += t2;
        __syncthreads();
    }
    if (tid < 256) {
        const int excl = sbase + off[tid] - v;
        const int g = (b << BSH) + tid;
        if (g < N_NODES) { deg[g] = v; row_beg[g] = excl; }
        off[tid] = excl;
    }
    __syncthreads();
    for (int i = tid; i < m; i += 512) {
        const int p = packed[base_in + i];
        const int pos = atomicAdd(&off[p & BMASK], 1);
        csr[pos] = p >> BSH;
    }
}

// ---------------------------------------------------------------------------
// GEMM1, r10 structure with the vmcnt-pollution fix: W1 staged to LDS ONCE
// per block (compute-phase W reads are uniform ds_read = lgkmcnt domain),
// so vmcnt is owned exclusively by the x gload_lds prefetches and counted
// vmcnt(8) keeps the double-buffered pipeline in flight across barriers.
// 128 rows/block, KT=32 -> LDS = 32K(W) + 2x16K(x dbuf) = 64KB, 2 blk/CU.
// XOR swizzle both sides (rule #21): global slot = (l&7)^(l>>3&7), read
// slot = c ^ (row&7) -> conflict-free ds_read_b128.
__global__ __launch_bounds__(128) void gemm1_kernel(
    const float* __restrict__ x, const float* __restrict__ W1,
    const int* __restrict__ deg, float* __restrict__ hs1,
    float* __restrict__ dis, int n)
{
    __shared__ float wsh[F_IN * H1];                               // 32 KB
    __shared__ __attribute__((aligned(16))) float xt[2][GR * GKT]; // 32 KB

    const int tid = threadIdx.x;      // 0..127
    const int wv  = tid >> 6;
    const int ln  = tid & 63;
    const int r0  = blockIdx.x * GR;

    // stage W1 (coalesced float4), drained by the syncthreads below
    for (int i = tid; i < F_IN * H1 / 4; i += 128)
        ((float4*)wsh)[i] = ((const float4*)W1)[i];

    const int lrow  = ln >> 3;          // row within 8-group
    const int lslot = ln & 7;           // local 16B slot
    const int gslot = lslot ^ lrow;     // pre-swizzled global slot

    auto issue = [&](int kt, int buf) {
        #pragma unroll
        for (int ii = 0; ii < 8; ++ii) {
            const int row_l = wv * 64 + ii * 8 + lrow;
            int row_g = r0 + row_l;
            if (row_g > n - 1) row_g = n - 1;          // clamp (last block)
            const float* g = x + (size_t)row_g * F_IN + kt * GKT + gslot * 4;
            float* l = &xt[buf][(wv * 64 + ii * 8) * GKT];  // uniform base
            __builtin_amdgcn_global_load_lds(
                (const __attribute__((address_space(1))) void*)g,
                (__attribute__((address_space(3))) void*)l,
                16, 0, 0);
        }
    };

    float acc[H1];
    #pragma unroll
    for (int j = 0; j < H1; ++j) acc[j] = 0.f;

    __syncthreads();                   // W staged; vmcnt/lgkmcnt drained
    issue(0, 0);

    for (int kt = 0; kt < GNT; ++kt) {
        const int buf = kt & 1;
        if (kt + 1 < GNT) {
            issue(kt + 1, buf ^ 1);
            asm volatile("s_waitcnt vmcnt(8)" ::: "memory");  // tile kt landed
        } else {
            asm volatile("s_waitcnt vmcnt(0)" ::: "memory");
        }
        __builtin_amdgcn_s_barrier();
        __builtin_amdgcn_sched_barrier(0);
        #pragma unroll
        for (int c = 0; c < 8; ++c) {
            const float4 xv =
                *(const float4*)&xt[buf][tid * GKT + ((c ^ (tid & 7)) << 2)];
            const float* wk = wsh + (kt * GKT + c * 4) * H1;  // uniform LDS
            #pragma unroll
            for (int j = 0; j < H1; ++j) {
                acc[j] = fmaf(xv.x, wk[j],          acc[j]);
                acc[j] = fmaf(xv.y, wk[H1 + j],     acc[j]);
                acc[j] = fmaf(xv.z, wk[2 * H1 + j], acc[j]);
                acc[j] = fmaf(xv.w, wk[3 * H1 + j], acc[j]);
            }
        }
        __builtin_amdgcn_s_barrier();  // protect buf before reissue
    }

    const int r = r0 + tid;
    if (r < n) {
        const float dv = rsqrtf((float)deg[r] + 1.0f);
        dis[r] = dv;
        float4* o = (float4*)(hs1 + (size_t)r * H1);
        #pragma unroll
        for (int q = 0; q < 4; ++q) {
            float4 v;
            v.x = acc[4 * q + 0] * dv;
            v.y = acc[4 * q + 1] * dv;
            v.z = acc[4 * q + 2] * dv;
            v.w = acc[4 * q + 3] * dv;
            o[q] = v;
        }
    }
}

// ---------------------------------------------------------------------------
// Pull1: 4-lane group per node; unroll-4 with batched index loads.
// Epilogue: c = dis * relu(dis*(acc + hs1_self) + b1).
__global__ __launch_bounds__(256) void pull1_kernel(
    const int* __restrict__ row_beg, const int* __restrict__ deg,
    const int* __restrict__ csr, const float* __restrict__ rows,
    const float* __restrict__ dis, const float* __restrict__ b1,
    float* __restrict__ out, int n)
{
    int t = blockIdx.x * 256 + threadIdx.x;
    int g = t >> 2;
    int q = t & 3;
    if (g >= n) return;
    const int beg = row_beg[g];
    const int end = beg + deg[g];
    float4 a0 = make_float4(0.f, 0.f, 0.f, 0.f);
    float4 a1 = make_float4(0.f, 0.f, 0.f, 0.f);
    int i = beg;
    for (; i + 3 < end; i += 4) {
        const int s0 = csr[i], s1 = csr[i + 1], s2 = csr[i + 2], s3 = csr[i + 3];
        float4 v0 = ((const float4*)(rows + (size_t)s0 * H1))[q];
        float4 v1 = ((const float4*)(rows + (size_t)s1 * H1))[q];
        float4 v2 = ((const float4*)(rows + (size_t)s2 * H1))[q];
        float4 v3 = ((const float4*)(rows + (size_t)s3 * H1))[q];
        a0.x += v0.x + v2.x; a0.y += v0.y + v2.y; a0.z += v0.z + v2.z; a0.w += v0.w + v2.w;
        a1.x += v1.x + v3.x; a1.y += v1.y + v3.y; a1.z += v1.z + v3.z; a1.w += v1.w + v3.w;
    }
    for (; i < end; ++i) {
        float4 v = ((const float4*)(rows + (size_t)csr[i] * H1))[q];
        a0.x += v.x; a0.y += v.y; a0.z += v.z; a0.w += v.w;
    }
    a0.x += a1.x; a0.y += a1.y; a0.z += a1.z; a0.w += a1.w;

    const float dv = dis[g];
    float4 h = ((const float4*)(rows + (size_t)g * H1))[q];  // self-loop
    float4 bq = ((const float4*)b1)[q];
    a0.x = dv * fmaxf(dv * (a0.x + h.x) + bq.x, 0.f);
    a0.y = dv * fmaxf(dv * (a0.y + h.y) + bq.y, 0.f);
    a0.z = dv * fmaxf(dv * (a0.z + h.z) + bq.z, 0.f);
    a0.w = dv * fmaxf(dv * (a0.w + h.w) + bq.w, 0.f);
    ((float4*)(out + (size_t)g * H1))[q] = a0;
}

// ---------------------------------------------------------------------------
// Fused pull2 + layer-2 epilogue: aggregate c (16-dim) per node, swap the
// full t[16] across the 4-lane group (12 shfl), apply W2 + b2 + log_softmax
// in-group, write out directly.
__global__ __launch_bounds__(256) void pull2_epi_kernel(
    const int* __restrict__ row_beg, const int* __restrict__ deg,
    const int* __restrict__ csr, const float* __restrict__ c,
    const float* __restrict__ W2, const float* __restrict__ b2,
    const float* __restrict__ dis, float* __restrict__ out, int n)
{
    __shared__ float w[H1 * H2];   // [16][40]
    __shared__ float bb[H2];
    for (int i = threadIdx.x; i < H1 * H2; i += 256) w[i] = W2[i];
    if (threadIdx.x < H2) bb[threadIdx.x] = b2[threadIdx.x];
    __syncthreads();

    int t = blockIdx.x * 256 + threadIdx.x;
    int g = t >> 2;
    int q = t & 3;
    if (g >= n) return;
    const int beg = row_beg[g];
    const int end = beg + deg[g];
    float4 a0 = make_float4(0.f, 0.f, 0.f, 0.f);
    float4 a1 = make_float4(0.f, 0.f, 0.f, 0.f);
    int i = beg;
    for (; i + 3 < end; i += 4) {
        const int s0 = csr[i], s1 = csr[i + 1], s2 = csr[i + 2], s3 = csr[i + 3];
        float4 v0 = ((const float4*)(c + (size_t)s0 * H1))[q];
        float4 v1 = ((const float4*)(c + (size_t)s1 * H1))[q];
        float4 v2 = ((const float4*)(c + (size_t)s2 * H1))[q];
        float4 v3 = ((const float4*)(c + (size_t)s3 * H1))[q];
        a0.x += v0.x + v2.x; a0.y += v0.y + v2.y; a0.z += v0.z + v2.z; a0.w += v0.w + v2.w;
        a1.x += v1.x + v3.x; a1.y += v1.y + v3.y; a1.z += v1.z + v3.z; a1.w += v1.w + v3.w;
    }
    for (; i < end; ++i) {
        float4 v = ((const float4*)(c + (size_t)csr[i] * H1))[q];
        a0.x += v.x; a0.y += v.y; a0.z += v.z; a0.w += v.w;
    }
    float4 sv = ((const float4*)(c + (size_t)g * H1))[q];    // self term
    float4 acc;
    acc.x = a0.x + a1.x + sv.x;
    acc.y = a0.y + a1.y + sv.y;
    acc.z = a0.z + a1.z + sv.z;
    acc.w = a0.w + a1.w + sv.w;

    // gather full t[16] across the aligned 4-lane group
    float tt[16];
    tt[4 * q + 0] = acc.x; tt[4 * q + 1] = acc.y;
    tt[4 * q + 2] = acc.z; tt[4 * q + 3] = acc.w;
    #pragma unroll
    for (int p = 1; p < 4; ++p) {
        const int qq = q ^ p;
        tt[4 * qq + 0] = __shfl_xor(acc.x, p, 64);
        tt[4 * qq + 1] = __shfl_xor(acc.y, p, 64);
        tt[4 * qq + 2] = __shfl_xor(acc.z, p, 64);
        tt[4 * qq + 3] = __shfl_xor(acc.w, p, 64);
    }

    const float dv = dis[g];
    float val[10];
    float m = -INFINITY;
    #pragma unroll
    for (int u = 0; u < 10; ++u) {
        const int j = q * 10 + u;
        float s = 0.f;
        #pragma unroll
        for (int k = 0; k < H1; ++k) s += tt[k] * w[k * H2 + j];
        val[u] = dv * s + bb[j];
        m = fmaxf(m, val[u]);
    }
    m = fmaxf(m, __shfl_xor(m, 1, 64));
    m = fmaxf(m, __shfl_xor(m, 2, 64));
    float ex = 0.f;
    #pragma unroll
    for (int u = 0; u < 10; ++u) ex += __expf(val[u] - m);
    ex += __shfl_xor(ex, 1, 64);
    ex += __shfl_xor(ex, 2, 64);
    const float lse = m + logf(ex);

    float2* o = (float2*)(out + (size_t)g * H2 + q * 10);
    #pragma unroll
    for (int u = 0; u < 5; ++u) {
        float2 v;
        v.x = val[2 * u]     - lse;
        v.y = val[2 * u + 1] - lse;
        o[u] = v;
    }
}

// ---------------------------------------------------------------------------
extern "C" void kernel_launch(void* const* d_in, const int* in_sizes, int n_in,
                              void* d_out, int out_size, void* d_ws, size_t ws_size,
                              hipStream_t stream)
{
    const float* x   = (const float*)d_in[0];
    const void*  ei  = d_in[1];                 // int32 or int64 [2, E] — detected
    const float* W1  = (const float*)d_in[2];
    const float* b1  = (const float*)d_in[3];
    const float* W2  = (const float*)d_in[4];
    const float* b2  = (const float*)d_in[5];
    float*       out = (float*)d_out;

    // workspace layout (4-byte units); ~28.4 MB, float4-aligned slabs.
    // packed (391*CAP slotted, 14.4MB) is time-multiplexed:
    //   CSR build: packed;   gemm1/pulls: hs1/c overlay its first 12.8MB
    int*   base    = (int*)d_ws;
    int*   flag    = base;                                  // 16
    int*   deg     = base + 16;                             // N
    int*   row_beg = deg + N_NODES;                         // N
    int*   cnt     = row_beg + N_NODES;                     // 512 (NB used)
    float* dis     = (float*)(cnt + 512);                   // N
    int*   csr     = (int*)(dis + N_NODES);                 // E (dense)
    int*   packed  = csr + N_EDGES;                         // NB*CAP (slotted)
    float* hs1     = (float*)packed;                        // N*16 overlay
    float* c       = hs1 + (size_t)N_NODES * H1;            // N*16 overlay

    detect_idx_kernel<<<1, 64, 0, stream>>>((const int*)ei, flag, cnt);

    scatter_atomic_kernel<<<B1, 256, 0, stream>>>(ei, flag, cnt, packed);
    bucket_csr_kernel<<<NB, 512, 0, stream>>>(packed, cnt, deg, row_beg, csr);

    gemm1_kernel<<<(N_NODES + GR - 1) / GR, 128, 0, stream>>>(x, W1, deg, hs1, dis, N_NODES);

    const int PB = (N_NODES * 4 + 255) / 256;
    pull1_kernel<<<PB, 256, 0, stream>>>(row_beg, deg, csr, hs1, dis, b1, c, N_NODES);
    pull2_epi_kernel<<<PB, 256, 0, stream>>>(row_beg, deg, csr, c, W2, b2, dis, out, N_NODES);
}

// Round 17
// 261.446 us; speedup vs baseline: 1.4493x; 1.1650x over previous
//
#include <hip/hip_runtime.h>
#include <math.h>

#define N_NODES 100000
#define N_EDGES 3200000
#define F_IN    512
#define H1      16
#define H2      40

#define NB      391      // coarse buckets: dst >> 8, 256 nodes each
#define BSH     8
#define BMASK   255
#define B1      512      // scatter blocks
#define EPB     6250     // edges per block (512*6250 = 3.2M exactly)
#define CAP     9216     // bucket slot capacity: mean 8192 + 11 sigma (fixed input)

// ---------------------------------------------------------------------------
// Detect edge_index dtype (int64 vs int32) and zero the bucket counters.
__global__ void detect_idx_kernel(const int* __restrict__ ei, int* __restrict__ flag,
                                  int* __restrict__ cnt)
{
    for (int i = threadIdx.x; i < 512; i += 64) cnt[i] = 0;
    if (threadIdx.x == 0) {
        int all_zero = 1;
        for (int i = 0; i < 64; ++i)
            if (ei[2 * i + 1] != 0) { all_zero = 0; break; }
        *flag = all_zero;  // 1 => int64 layout, 0 => int32 layout
    }
}

__device__ __forceinline__ int edge_src(const void* ei, int e, int is64)
{
    return is64 ? (int)((const long long*)ei)[e] : ((const int*)ei)[e];
}
__device__ __forceinline__ int edge_dst(const void* ei, int e, int is64)
{
    return is64 ? (int)((const long long*)ei)[N_EDGES + e]
                : ((const int*)ei)[N_EDGES + e];
}

// ---------------------------------------------------------------------------
// Bucket scatter: LDS histogram; one global atomicAdd per touched bucket
// reserves this block's range in the bucket's CAP slot; LDS-cursor scatter.
__global__ __launch_bounds__(256) void scatter_atomic_kernel(
    const void* __restrict__ ei, const int* __restrict__ flag,
    int* __restrict__ cnt, int* __restrict__ packed)
{
    __shared__ int h[NB];
    __shared__ int cur[NB];
    for (int i = threadIdx.x; i < NB; i += 256) h[i] = 0;
    __syncthreads();
    const int is64 = *flag;
    const int e0 = blockIdx.x * EPB;
    for (int i = threadIdx.x; i < EPB; i += 256) {
        int e = e0 + i;
        if (e < N_EDGES) atomicAdd(&h[edge_dst(ei, e, is64) >> BSH], 1);
    }
    __syncthreads();
    for (int i = threadIdx.x; i < NB; i += 256) {
        int base = (h[i] > 0) ? atomicAdd(&cnt[i], h[i]) : 0;
        cur[i] = i * CAP + base;
    }
    __syncthreads();
    for (int i = threadIdx.x; i < EPB; i += 256) {
        int e = e0 + i;
        if (e >= N_EDGES) break;
        const int s = edge_src(ei, e, is64);
        const int d = edge_dst(ei, e, is64);
        const int pos = atomicAdd(&cur[d >> BSH], 1);
        packed[pos] = (s << BSH) | (d & BMASK);
    }
}

// ---------------------------------------------------------------------------
// One block per bucket: dense-csr base = wave-sum cnt[0..b); LDS hist+scan+
// scatter. Emits deg[], row_beg[] (global), csr[].
__global__ __launch_bounds__(512) void bucket_csr_kernel(
    const int* __restrict__ packed, const int* __restrict__ cnt,
    int* __restrict__ deg, int* __restrict__ row_beg, int* __restrict__ csr)
{
    __shared__ int hist[256];
    __shared__ int off[256];
    __shared__ int sbase;
    const int b   = blockIdx.x;
    const int tid = threadIdx.x;

    if (tid < 64) {
        int s = 0;
        for (int i = tid; i < b; i += 64) s += cnt[i];
        #pragma unroll
        for (int o = 32; o > 0; o >>= 1) s += __shfl_xor(s, o, 64);
        if (tid == 0) sbase = s;
    }
    if (tid < 256) hist[tid] = 0;
    __syncthreads();

    const int base_in = b * CAP;
    const int m       = cnt[b];
    for (int i = tid; i < m; i += 512)
        atomicAdd(&hist[packed[base_in + i] & BMASK], 1);
    __syncthreads();

    int v = 0;
    if (tid < 256) { v = hist[tid]; off[tid] = v; }
    __syncthreads();
    for (int o = 1; o < 256; o <<= 1) {
        int t2 = 0;
        if (tid < 256 && tid >= o) t2 = off[tid - o];
        __syncthreads();
        if (tid < 256) off[tid] += t2;
        __syncthreads();
    }
    if (tid < 256) {
        const int excl = sbase + off[tid] - v;
        const int g = (b << BSH) + tid;
        if (g < N_NODES) { deg[g] = v; row_beg[g] = excl; }
        off[tid] = excl;
    }
    __syncthreads();
    for (int i = tid; i < m; i += 512) {
        const int p = packed[base_in + i];
        const int pos = atomicAdd(&off[p & BMASK], 1);
        csr[pos] = p >> BSH;
    }
}

// ---------------------------------------------------------------------------
// hs1[r][j] = (x[r] @ W1)[j] * dis[r];  dis[r] = rsqrt(deg[r]+1)
// FROZEN at the r6/r12 config (~87 us): thread per row, 256-thr blocks,
// W1 direct from global at wave-uniform addresses, unroll 2. Six alternate
// mechanisms (r7/r9/r10/r14/r15/r16) all measured worse — this pattern's
// {L1-reuse x in-flight-lines x waves} equilibrium is the practical floor.
__global__ __launch_bounds__(256) void gemm1_kernel(
    const float* __restrict__ x, const float* __restrict__ W1,
    const int* __restrict__ deg, float* __restrict__ hs1,
    float* __restrict__ dis, int n)
{
    const int r = blockIdx.x * 256 + threadIdx.x;
    if (r >= n) return;

    const float4* xr = (const float4*)(x + (size_t)r * F_IN);
    float acc[H1];
    #pragma unroll
    for (int j = 0; j < H1; ++j) acc[j] = 0.f;

    #pragma unroll 2
    for (int k4 = 0; k4 < F_IN / 4; ++k4) {
        const float4 xv = xr[k4];
        const float* wk = W1 + k4 * 4 * H1;        // wave-uniform address
        #pragma unroll
        for (int j = 0; j < H1; ++j)
            acc[j] += xv.x * wk[j] + xv.y * wk[H1 + j]
                    + xv.z * wk[2 * H1 + j] + xv.w * wk[3 * H1 + j];
    }

    const float dv = rsqrtf((float)deg[r] + 1.0f);
    dis[r] = dv;
    float4* o = (float4*)(hs1 + (size_t)r * H1);
    #pragma unroll
    for (int q = 0; q < 4; ++q) {
        float4 v;
        v.x = acc[4 * q + 0] * dv;
        v.y = acc[4 * q + 1] * dv;
        v.z = acc[4 * q + 2] * dv;
        v.w = acc[4 * q + 3] * dv;
        o[q] = v;
    }
}

// ---------------------------------------------------------------------------
// Pull1: 4-lane group per node; unroll-4 with batched index loads.
// Epilogue: c = dis * relu(dis*(acc + hs1_self) + b1).
__global__ __launch_bounds__(256) void pull1_kernel(
    const int* __restrict__ row_beg, const int* __restrict__ deg,
    const int* __restrict__ csr, const float* __restrict__ rows,
    const float* __restrict__ dis, const float* __restrict__ b1,
    float* __restrict__ out, int n)
{
    int t = blockIdx.x * 256 + threadIdx.x;
    int g = t >> 2;
    int q = t & 3;
    if (g >= n) return;
    const int beg = row_beg[g];
    const int end = beg + deg[g];
    float4 a0 = make_float4(0.f, 0.f, 0.f, 0.f);
    float4 a1 = make_float4(0.f, 0.f, 0.f, 0.f);
    int i = beg;
    for (; i + 3 < end; i += 4) {
        const int s0 = csr[i], s1 = csr[i + 1], s2 = csr[i + 2], s3 = csr[i + 3];
        float4 v0 = ((const float4*)(rows + (size_t)s0 * H1))[q];
        float4 v1 = ((const float4*)(rows + (size_t)s1 * H1))[q];
        float4 v2 = ((const float4*)(rows + (size_t)s2 * H1))[q];
        float4 v3 = ((const float4*)(rows + (size_t)s3 * H1))[q];
        a0.x += v0.x + v2.x; a0.y += v0.y + v2.y; a0.z += v0.z + v2.z; a0.w += v0.w + v2.w;
        a1.x += v1.x + v3.x; a1.y += v1.y + v3.y; a1.z += v1.z + v3.z; a1.w += v1.w + v3.w;
    }
    for (; i < end; ++i) {
        float4 v = ((const float4*)(rows + (size_t)csr[i] * H1))[q];
        a0.x += v.x; a0.y += v.y; a0.z += v.z; a0.w += v.w;
    }
    a0.x += a1.x; a0.y += a1.y; a0.z += a1.z; a0.w += a1.w;

    const float dv = dis[g];
    float4 h = ((const float4*)(rows + (size_t)g * H1))[q];  // self-loop
    float4 bq = ((const float4*)b1)[q];
    a0.x = dv * fmaxf(dv * (a0.x + h.x) + bq.x, 0.f);
    a0.y = dv * fmaxf(dv * (a0.y + h.y) + bq.y, 0.f);
    a0.z = dv * fmaxf(dv * (a0.z + h.z) + bq.z, 0.f);
    a0.w = dv * fmaxf(dv * (a0.w + h.w) + bq.w, 0.f);
    ((float4*)(out + (size_t)g * H1))[q] = a0;
}

// ---------------------------------------------------------------------------
// Fused pull2 + layer-2 epilogue: aggregate c (16-dim) per node, swap the
// full t[16] across the 4-lane group (12 shfl), apply W2 + b2 + log_softmax
// in-group, write out directly.
__global__ __launch_bounds__(256) void pull2_epi_kernel(
    const int* __restrict__ row_beg, const int* __restrict__ deg,
    const int* __restrict__ csr, const float* __restrict__ c,
    const float* __restrict__ W2, const float* __restrict__ b2,
    const float* __restrict__ dis, float* __restrict__ out, int n)
{
    __shared__ float w[H1 * H2];   // [16][40]
    __shared__ float bb[H2];
    for (int i = threadIdx.x; i < H1 * H2; i += 256) w[i] = W2[i];
    if (threadIdx.x < H2) bb[threadIdx.x] = b2[threadIdx.x];
    __syncthreads();

    int t = blockIdx.x * 256 + threadIdx.x;
    int g = t >> 2;
    int q = t & 3;
    if (g >= n) return;
    const int beg = row_beg[g];
    const int end = beg + deg[g];
    float4 a0 = make_float4(0.f, 0.f, 0.f, 0.f);
    float4 a1 = make_float4(0.f, 0.f, 0.f, 0.f);
    int i = beg;
    for (; i + 3 < end; i += 4) {
        const int s0 = csr[i], s1 = csr[i + 1], s2 = csr[i + 2], s3 = csr[i + 3];
        float4 v0 = ((const float4*)(c + (size_t)s0 * H1))[q];
        float4 v1 = ((const float4*)(c + (size_t)s1 * H1))[q];
        float4 v2 = ((const float4*)(c + (size_t)s2 * H1))[q];
        float4 v3 = ((const float4*)(c + (size_t)s3 * H1))[q];
        a0.x += v0.x + v2.x; a0.y += v0.y + v2.y; a0.z += v0.z + v2.z; a0.w += v0.w + v2.w;
        a1.x += v1.x + v3.x; a1.y += v1.y + v3.y; a1.z += v1.z + v3.z; a1.w += v1.w + v3.w;
    }
    for (; i < end; ++i) {
        float4 v = ((const float4*)(c + (size_t)csr[i] * H1))[q];
        a0.x += v.x; a0.y += v.y; a0.z += v.z; a0.w += v.w;
    }
    float4 sv = ((const float4*)(c + (size_t)g * H1))[q];    // self term
    float4 acc;
    acc.x = a0.x + a1.x + sv.x;
    acc.y = a0.y + a1.y + sv.y;
    acc.z = a0.z + a1.z + sv.z;
    acc.w = a0.w + a1.w + sv.w;

    // gather full t[16] across the aligned 4-lane group
    float tt[16];
    tt[4 * q + 0] = acc.x; tt[4 * q + 1] = acc.y;
    tt[4 * q + 2] = acc.z; tt[4 * q + 3] = acc.w;
    #pragma unroll
    for (int p = 1; p < 4; ++p) {
        const int qq = q ^ p;
        tt[4 * qq + 0] = __shfl_xor(acc.x, p, 64);
        tt[4 * qq + 1] = __shfl_xor(acc.y, p, 64);
        tt[4 * qq + 2] = __shfl_xor(acc.z, p, 64);
        tt[4 * qq + 3] = __shfl_xor(acc.w, p, 64);
    }

    const float dv = dis[g];
    float val[10];
    float m = -INFINITY;
    #pragma unroll
    for (int u = 0; u < 10; ++u) {
        const int j = q * 10 + u;
        float s = 0.f;
        #pragma unroll
        for (int k = 0; k < H1; ++k) s += tt[k] * w[k * H2 + j];
        val[u] = dv * s + bb[j];
        m = fmaxf(m, val[u]);
    }
    m = fmaxf(m, __shfl_xor(m, 1, 64));
    m = fmaxf(m, __shfl_xor(m, 2, 64));
    float ex = 0.f;
    #pragma unroll
    for (int u = 0; u < 10; ++u) ex += __expf(val[u] - m);
    ex += __shfl_xor(ex, 1, 64);
    ex += __shfl_xor(ex, 2, 64);
    const float lse = m + logf(ex);

    float2* o = (float2*)(out + (size_t)g * H2 + q * 10);
    #pragma unroll
    for (int u = 0; u < 5; ++u) {
        float2 v;
        v.x = val[2 * u]     - lse;
        v.y = val[2 * u + 1] - lse;
        o[u] = v;
    }
}

// ---------------------------------------------------------------------------
extern "C" void kernel_launch(void* const* d_in, const int* in_sizes, int n_in,
                              void* d_out, int out_size, void* d_ws, size_t ws_size,
                              hipStream_t stream)
{
    const float* x   = (const float*)d_in[0];
    const void*  ei  = d_in[1];                 // int32 or int64 [2, E] — detected
    const float* W1  = (const float*)d_in[2];
    const float* b1  = (const float*)d_in[3];
    const float* W2  = (const float*)d_in[4];
    const float* b2  = (const float*)d_in[5];
    float*       out = (float*)d_out;

    // workspace layout (4-byte units); ~28.4 MB, float4-aligned slabs.
    // packed (391*CAP slotted, 14.4MB) is time-multiplexed:
    //   CSR build: packed;   gemm1/pulls: hs1/c overlay its first 12.8MB
    int*   base    = (int*)d_ws;
    int*   flag    = base;                                  // 16
    int*   deg     = base + 16;                             // N
    int*   row_beg = deg + N_NODES;                         // N
    int*   cnt     = row_beg + N_NODES;                     // 512 (NB used)
    float* dis     = (float*)(cnt + 512);                   // N
    int*   csr     = (int*)(dis + N_NODES);                 // E (dense)
    int*   packed  = csr + N_EDGES;                         // NB*CAP (slotted)
    float* hs1     = (float*)packed;                        // N*16 overlay
    float* c       = hs1 + (size_t)N_NODES * H1;            // N*16 overlay

    detect_idx_kernel<<<1, 64, 0, stream>>>((const int*)ei, flag, cnt);

    scatter_atomic_kernel<<<B1, 256, 0, stream>>>(ei, flag, cnt, packed);
    bucket_csr_kernel<<<NB, 512, 0, stream>>>(packed, cnt, deg, row_beg, csr);

    gemm1_kernel<<<(N_NODES + 255) / 256, 256, 0, stream>>>(x, W1, deg, hs1, dis, N_NODES);

    const int PB = (N_NODES * 4 + 255) / 256;
    pull1_kernel<<<PB, 256, 0, stream>>>(row_beg, deg, csr, hs1, dis, b1, c, N_NODES);
    pull2_epi_kernel<<<PB, 256, 0, stream>>>(row_beg, deg, csr, c, W2, b2, dis, out, N_NODES);
}